// Round 2
// baseline (770.433 us; speedup 1.0000x reference)
//
#include <hip/hip_runtime.h>
#include <stdint.h>

// GruTl: tensor-factorized GRU, N=64, L=128, modes (32,16,8) -> (32,16,8).
// R4: R3's LDS-traffic cut, with pack4 reverted to the validated f2bf integer
// path (R3's v_cvt_pk_bf16_f32 inline asm produced NaN; see journal).
// GEMM2 wave ownership: (d-tile = w&1, ef-tiles {w>>1, w>>1+4}) so each wave
// reads only its own 16-row t1 d-panel (12 ds_read_b128/step vs 24), A-frags
// reused across its two ef-tiles; kron B-frags doubled in registers.

constexpr int kN = 64;
constexpr int kL = 128;
constexpr int kA = 32, kB = 16, kC = 8;
constexpr int kBC = kB * kC;       // 128
constexpr int kTot = kA * kBC;     // 4096 elements per (n,l) tile
constexpr int kTS = kBC + 4;       // fused-fallback LDS stride
constexpr int kTh = 512;

constexpr int kHTS = 40;           // hT/xT row stride in bf16 (32 + 8 pad, 16B-aligned rows)
constexpr int kT1S = 136;          // t1L row stride in bf16 (128 + 8 pad)

typedef __attribute__((ext_vector_type(8))) short bf16x8;
typedef __attribute__((ext_vector_type(4))) float f32x4;

namespace {

__device__ __forceinline__ float bf2f(unsigned int u) { return __uint_as_float(u << 16); }
__device__ __forceinline__ unsigned int f2bf(float v) {
  unsigned int u = __float_as_uint(v);
  return (u + 0x7fffu + ((u >> 16) & 1u)) >> 16;   // round-to-nearest-even
}
__device__ __forceinline__ float sigmoid_f(float x) {
  return __fdividef(1.f, 1.f + __expf(-x));
}
__device__ __forceinline__ float tanh_f(float x) {
  return 1.f - __fdividef(2.f, 1.f + __expf(2.f * x));
}

__device__ __forceinline__ bf16x8 frag_from_lds(const unsigned short* p) {
  uint4 u = *(const uint4*)p;
  return __builtin_bit_cast(bf16x8, u);
}
// 8 consecutive f32 -> bf16 frag (element j = input j)
__device__ __forceinline__ bf16x8 frag_from_f32(const float* p) {
  float4 a = ((const float4*)p)[0];
  float4 b = ((const float4*)p)[1];
  uint4 u;
  u.x = f2bf(a.x) | (f2bf(a.y) << 16);
  u.y = f2bf(a.z) | (f2bf(a.w) << 16);
  u.z = f2bf(b.x) | (f2bf(b.y) << 16);
  u.w = f2bf(b.z) | (f2bf(b.w) << 16);
  return __builtin_bit_cast(bf16x8, u);
}
__device__ __forceinline__ uint2 pack4(const f32x4& a) {
  uint2 p;
  p.x = f2bf(a[0]) | (f2bf(a[1]) << 16);
  p.y = f2bf(a[2]) | (f2bf(a[3]) << 16);
  return p;
}

// ---------------- kron precompute: kW/kU[g][ef][bc] = M2[g][e][b]*M3[g][f][c]
__global__ void kron_kernel(const float* __restrict__ W2, const float* __restrict__ W3,
                            const float* __restrict__ U2, const float* __restrict__ U3,
                            unsigned short* __restrict__ kW, unsigned short* __restrict__ kU) {
  int i = blockIdx.x * 256 + threadIdx.x;           // 0 .. 98303
  const float* M2 = W2; const float* M3 = W3; unsigned short* dst = kW;
  int j = i;
  if (i >= 3 * 128 * 128) { M2 = U2; M3 = U3; dst = kU; j = i - 3 * 128 * 128; }
  int g = j >> 14, ef = (j >> 7) & 127, bc = j & 127;
  int e = ef >> 3, f = ef & 7, b = bc >> 3, c = bc & 7;
  float v = M2[(g * 16 + e) * 16 + b] * M3[(g * 8 + f) * 8 + c];
  dst[j] = (unsigned short)f2bf(v);
}

// Shared GEMM1: out1T[bc][d] = sum_a srcT[bc][a] * M1T[a][d], written as t1L[d][bc].
// Wave w owns bc-tile w. a-frag = srcT row (w*16+r), cols q*8..+8, reused for 3 gates.
__device__ __forceinline__ void gemm1(const unsigned short* __restrict__ srcT,
                                      const bf16x8 bW[3][2],
                                      unsigned short (*__restrict__ t1L)[kA * kT1S],
                                      int w, int q, int r) {
  bf16x8 ah = frag_from_lds(srcT + (w * 16 + r) * kHTS + q * 8);
#pragma unroll
  for (int g = 0; g < 3; ++g) {
#pragma unroll
    for (int nt = 0; nt < 2; ++nt) {
      f32x4 acc = {0.f, 0.f, 0.f, 0.f};
      acc = __builtin_amdgcn_mfma_f32_16x16x32_bf16(ah, bW[g][nt], acc, 0, 0, 0);
      // D[bc = w*16+q*4+i][d = nt*16+r] -> t1L[g][d][bc], 4 consecutive bc
      *(uint2*)&t1L[g][(nt * 16 + r) * kT1S + w * 16 + q * 4] = pack4(acc);
    }
  }
}

// Shared GEMM2 (R3/R4 assignment): wave owns d-tile mtw = w&1 and ef-tiles
// {efb, efb+4} (efb = w>>1). A-frags depend only on (mtw,kc) -> 12 ds_read_b128
// per wave per step (4x less than R2), reused across the 2 ef-tiles.
// out2[g][eft]: D[d = mtw*16+q*4+i][ef = (efb+4*eft)*16+r]
__device__ __forceinline__ void gemm2(const unsigned short (*__restrict__ t1L)[kA * kT1S],
                                      const bf16x8 bK[3][2][4],
                                      f32x4 out2[3][2],
                                      int mtw, int q, int r) {
  const int abase = (mtw * 16 + r) * kT1S + q * 8;
#pragma unroll
  for (int g = 0; g < 3; ++g) {
    bf16x8 af[4];
#pragma unroll
    for (int kc = 0; kc < 4; ++kc)
      af[kc] = frag_from_lds(&t1L[g][abase + kc * 32]);
#pragma unroll
    for (int eft = 0; eft < 2; ++eft) {
      f32x4 acc = {0.f, 0.f, 0.f, 0.f};
#pragma unroll
      for (int kc = 0; kc < 4; ++kc)
        acc = __builtin_amdgcn_mfma_f32_16x16x32_bf16(af[kc], bK[g][eft][kc], acc, 0, 0, 0);
      out2[g][eft] = acc;
    }
  }
}

// Load B-frags: bK[g][eft][kc] (kron rows ef = (efb+4*eft)*16+r), bW[g][nt] from M1 (f32)
__device__ __forceinline__ void load_bfrags(const unsigned short* __restrict__ kron,
                                            const float* __restrict__ M1,
                                            bf16x8 bK[3][2][4], bf16x8 bW[3][2],
                                            int efb, int q, int r) {
#pragma unroll
  for (int g = 0; g < 3; ++g) {
#pragma unroll
    for (int eft = 0; eft < 2; ++eft)
#pragma unroll
      for (int kc = 0; kc < 4; ++kc)
        bK[g][eft][kc] = frag_from_lds(
            kron + ((g * 128 + (efb + 4 * eft) * 16 + r) * 128 + kc * 32 + q * 8));
#pragma unroll
    for (int nt = 0; nt < 2; ++nt)
      bW[g][nt] = frag_from_f32(M1 + (g * 32 + nt * 16 + r) * 32 + q * 8);
  }
}

// ---------------- kernel A: XW precompute via MFMA, one block per (n,l) --------
__global__ __launch_bounds__(kTh) void xw_mfma(
    const float* __restrict__ x, const float* __restrict__ W1,
    const unsigned short* __restrict__ kW, unsigned short* __restrict__ xw) {
  __shared__ __align__(16) unsigned short xT[kBC * kHTS];
  __shared__ __align__(16) unsigned short t1L[3][kA * kT1S];
  const int tid = threadIdx.x;
  const int blk = blockIdx.x;                       // n*L + t
  const int w = tid >> 6, l = tid & 63, q = l >> 4, r = l & 15;
  const int mtw = w & 1, efb = w >> 1;

  bf16x8 bK[3][2][4], bW[3][2];
  load_bfrags(kW, W1, bK, bW, efb, q, r);

  // stage x tile -> xT[bc][a] (bf16). thread: fixed bc, 8 consecutive a.
  {
    const int bc = tid & 127, a0 = (tid >> 7) * 8;
    const float* xg = x + (size_t)blk * kTot + bc;
    uint4 u;
    u.x = f2bf(xg[(a0 + 0) * kBC]) | (f2bf(xg[(a0 + 1) * kBC]) << 16);
    u.y = f2bf(xg[(a0 + 2) * kBC]) | (f2bf(xg[(a0 + 3) * kBC]) << 16);
    u.z = f2bf(xg[(a0 + 4) * kBC]) | (f2bf(xg[(a0 + 5) * kBC]) << 16);
    u.w = f2bf(xg[(a0 + 6) * kBC]) | (f2bf(xg[(a0 + 7) * kBC]) << 16);
    *(uint4*)&xT[bc * kHTS + a0] = u;
  }
  __syncthreads();
  gemm1(xT, bW, t1L, w, q, r);
  __syncthreads();
  f32x4 out2[3][2];
  gemm2(t1L, bK, out2, mtw, q, r);
  // store fragment-ordered bf16: pos = tid*8 + eft*4 + i (matches scan's unpack)
#pragma unroll
  for (int g = 0; g < 3; ++g) {
    uint4 u;
    uint2 p0 = pack4(out2[g][0]), p1 = pack4(out2[g][1]);
    u.x = p0.x; u.y = p0.y; u.z = p1.x; u.w = p1.y;
    *(uint4*)(xw + ((size_t)blk * 3 + g) * kTot + tid * 8) = u;
  }
}

// ---------------- kernel B: MFMA scan, one block per n ----------------
__global__ __launch_bounds__(kTh) void scan_mfma(
    const unsigned short* __restrict__ xw, const float* __restrict__ U1,
    const unsigned short* __restrict__ kU,
    float* __restrict__ outs, float* __restrict__ hlast) {
  __shared__ __align__(16) unsigned short hT[kBC * kHTS];
  __shared__ __align__(16) unsigned short t1L[3][kA * kT1S];
  const int tid = threadIdx.x;
  const int n = blockIdx.x;
  const int w = tid >> 6, l = tid & 63, q = l >> 4, r = l & 15;
  const int mtw = w & 1, efb = w >> 1;
  const int dbase = mtw * 16 + q * 4;

  bf16x8 bK[3][2][4], bW[3][2];
  load_bfrags(kU, U1, bK, bW, efb, q, r);

  // zero hT
  for (int i = tid; i < kBC * kHTS / 2; i += kTh) ((unsigned int*)hT)[i] = 0u;
  float hreg[2][4] = {{0.f, 0.f, 0.f, 0.f}, {0.f, 0.f, 0.f, 0.f}};

  const unsigned short* xp = xw + (size_t)n * kL * 3 * kTot + tid * 8;
  unsigned int xc[3][4];
#pragma unroll
  for (int g = 0; g < 3; ++g) {
    uint4 u = *(const uint4*)(xp + g * kTot);
    xc[g][0] = u.x; xc[g][1] = u.y; xc[g][2] = u.z; xc[g][3] = u.w;
  }
  __syncthreads();

  for (int t = 0; t < kL; ++t) {
    // prefetch next step's xw
    unsigned int xn[3][4];
    {
      const unsigned short* xq = xp + (size_t)((t + 1 < kL) ? t + 1 : t) * 3 * kTot;
#pragma unroll
      for (int g = 0; g < 3; ++g) {
        uint4 u = *(const uint4*)(xq + g * kTot);
        xn[g][0] = u.x; xn[g][1] = u.y; xn[g][2] = u.z; xn[g][3] = u.w;
      }
    }
    gemm1(hT, bW, t1L, w, q, r);
    __syncthreads();
    f32x4 hu[3][2];
    gemm2(t1L, bK, hu, mtw, q, r);

    // elementwise GRU on owned elements (d = dbase+i, ef = (efb+4*eft)*16+r)
    const size_t obase = ((size_t)n * kL + t) * kTot;
#pragma unroll
    for (int eft = 0; eft < 2; ++eft) {
      const int ef = (efb + 4 * eft) * 16 + r;
#pragma unroll
      for (int i = 0; i < 4; ++i) {
        const int e2 = eft * 4 + i;
        float x0 = bf2f((e2 & 1) ? (xc[0][e2 >> 1] >> 16) : (xc[0][e2 >> 1] & 0xffffu));
        float x1 = bf2f((e2 & 1) ? (xc[1][e2 >> 1] >> 16) : (xc[1][e2 >> 1] & 0xffffu));
        float x2 = bf2f((e2 & 1) ? (xc[2][e2 >> 1] >> 16) : (xc[2][e2 >> 1] & 0xffffu));
        float z  = sigmoid_f(x0 + hu[0][eft][i]);
        float rr = sigmoid_f(x1 + hu[1][eft][i]);
        float hc = tanh_f(x2 + rr * hu[2][eft][i]);
        float hn = z * hreg[eft][i] + (1.f - z) * hc;
        hreg[eft][i] = hn;
        outs[obase + (size_t)(dbase + i) * kBC + ef] = hn;
      }
      // write updated h (bf16) for next step's GEMM1: hT[ef][d], 4 consecutive d
      uint2 p;
      p.x = f2bf(hreg[eft][0]) | (f2bf(hreg[eft][1]) << 16);
      p.y = f2bf(hreg[eft][2]) | (f2bf(hreg[eft][3]) << 16);
      *(uint2*)&hT[ef * kHTS + dbase] = p;
    }
#pragma unroll
    for (int g = 0; g < 3; ++g)
#pragma unroll
      for (int u = 0; u < 4; ++u) xc[g][u] = xn[g][u];
    __syncthreads();
  }
#pragma unroll
  for (int eft = 0; eft < 2; ++eft) {
    const int ef = (efb + 4 * eft) * 16 + r;
#pragma unroll
    for (int i = 0; i < 4; ++i)
      hlast[(size_t)n * kTot + (size_t)(dbase + i) * kBC + ef] = hreg[eft][i];
  }
}

// ---------------- fallback: fully fused fp32 (validated structure, slow) -------
__device__ __forceinline__ int rfl(int v) { return __builtin_amdgcn_readfirstlane(v); }

__device__ __forceinline__ void load8f(const float* p, float* v) {
  float4 a = ((const float4*)p)[0];
  float4 b = ((const float4*)p)[1];
  v[0]=a.x; v[1]=a.y; v[2]=a.z; v[3]=a.w;
  v[4]=b.x; v[5]=b.y; v[6]=b.z; v[7]=b.w;
}
__device__ __forceinline__ void store8f(float* p, const float* v) {
  ((float4*)p)[0] = make_float4(v[0],v[1],v[2],v[3]);
  ((float4*)p)[1] = make_float4(v[4],v[5],v[6],v[7]);
}

__device__ __forceinline__ void mode1(const float* __restrict__ src,
                                      const float* __restrict__ Wg,
                                      float* __restrict__ t1, int tid) {
  const int w = rfl(tid >> 6);
  const int lane = tid & 63;
  const int bc = ((w & 1) << 6) | lane;
  const int dq = (w >> 1) << 3;
  float xr[kA];
#pragma unroll
  for (int a = 0; a < kA; ++a) xr[a] = src[a * kBC + bc];
  const float* wp = Wg + dq * kA;
#pragma unroll
  for (int dd = 0; dd < 8; ++dd) {
    float s = 0.f;
#pragma unroll
    for (int a = 0; a < kA; ++a) s += wp[dd * kA + a] * xr[a];
    t1[(dq + dd) * kTS + bc] = s;
  }
}
__device__ __forceinline__ void mode2(const float* __restrict__ t1,
                                      const float* __restrict__ Wg,
                                      float* __restrict__ t2, int tid) {
  const int w = rfl(tid >> 6);
  const int lane = tid & 63;
  const int d = ((w >> 1) << 3) | (lane >> 3);
  const int c = lane & 7;
  const int eh = (w & 1) << 3;
  float tr[kB];
#pragma unroll
  for (int b = 0; b < kB; ++b) tr[b] = t1[d * kTS + b * kC + c];
#pragma unroll
  for (int ee = 0; ee < 8; ++ee) {
    const int e = eh + ee;
    float s = 0.f;
#pragma unroll
    for (int b = 0; b < kB; ++b) s += Wg[e * kB + b] * tr[b];
    t2[d * kTS + e * kC + c] = s;
  }
}
__device__ __forceinline__ void mode3(const float* __restrict__ t2,
                                      const float* __restrict__ Wg,
                                      float* __restrict__ out8, int tid) {
  const int e = tid & 15;
  const int d = tid >> 4;
  float tr[kC];
  load8f(t2 + d * kTS + e * kC, tr);
#pragma unroll
  for (int f = 0; f < kC; ++f) {
    float s = 0.f;
#pragma unroll
    for (int c = 0; c < kC; ++c) s += Wg[f * kC + c] * tr[c];
    out8[f] = s;
  }
}

__global__ __launch_bounds__(kTh) void fused_kernel(
    const float* __restrict__ x,
    const float* __restrict__ W1, const float* __restrict__ W2,
    const float* __restrict__ W3, const float* __restrict__ U1,
    const float* __restrict__ U2, const float* __restrict__ U3,
    float* __restrict__ outs, float* __restrict__ hlast) {
  __shared__ float h[kTot];
  __shared__ float xs[kTot];
  __shared__ float t1[kA * kTS];
  __shared__ float t2[kA * kTS];
  const int tid = threadIdx.x;
  const int n = blockIdx.x;
  for (int i = tid; i < kTot; i += kTh) h[i] = 0.f;
  const int off = tid * kC;
  float* hp = h + off;
  float hn[kC];
  for (int l = 0; l < kL; ++l) {
    const float4* xg = (const float4*)(x + ((size_t)n * kL + l) * kTot);
    float4 xa = xg[tid], xb = xg[tid + kTh];
    __syncthreads();
    float4* xs4 = (float4*)xs;
    xs4[tid] = xa;
    xs4[tid + kTh] = xb;
    __syncthreads();
    float xwv[3][kC], hu[3][kC];
#pragma unroll
    for (int g = 0; g < 3; ++g) {
      mode1(xs, W1 + g * kA * kA, t1, tid);
      __syncthreads();
      mode2(t1, W2 + g * kB * kB, t2, tid);
      __syncthreads();
      mode3(t2, W3 + g * kC * kC, xwv[g], tid);
    }
#pragma unroll
    for (int g = 0; g < 3; ++g) {
      mode1(h, U1 + g * kA * kA, t1, tid);
      __syncthreads();
      mode2(t1, U2 + g * kB * kB, t2, tid);
      __syncthreads();
      mode3(t2, U3 + g * kC * kC, hu[g], tid);
    }
    float ho[kC];
    load8f(hp, ho);
#pragma unroll
    for (int f = 0; f < kC; ++f) {
      float z  = sigmoid_f(xwv[0][f] + hu[0][f]);
      float rr = sigmoid_f(xwv[1][f] + hu[1][f]);
      float hh = tanh_f(xwv[2][f] + rr * hu[2][f]);
      hn[f] = z * ho[f] + (1.f - z) * hh;
    }
    store8f(hp, hn);
    store8f(outs + ((size_t)n * kL + l) * kTot + off, hn);
  }
  store8f(hlast + (size_t)n * kTot + off, hn);
}

}  // namespace

extern "C" void kernel_launch(void* const* d_in, const int* in_sizes, int n_in,
                              void* d_out, int out_size, void* d_ws, size_t ws_size,
                              hipStream_t stream) {
  const float* x  = (const float*)d_in[0];
  const float* W1 = (const float*)d_in[1];
  const float* W2 = (const float*)d_in[2];
  const float* W3 = (const float*)d_in[3];
  const float* U1 = (const float*)d_in[4];
  const float* U2 = (const float*)d_in[5];
  const float* U3 = (const float*)d_in[6];
  float* outs  = (float*)d_out;
  float* hlast = outs + (size_t)kN * kL * kTot;

  const size_t kron_elems = 3 * 128 * 128;                    // per kron matrix
  const size_t kron_bytes = 2 * kron_elems * sizeof(unsigned short);   // 96 KB
  const size_t xw_bytes   = (size_t)kN * kL * 3 * kTot * 2;   // ~201 MB bf16

  if (ws_size >= kron_bytes + xw_bytes) {
    unsigned short* kW  = (unsigned short*)d_ws;
    unsigned short* kU  = kW + kron_elems;
    unsigned short* xww = kU + kron_elems;
    kron_kernel<<<dim3(384), dim3(256), 0, stream>>>(W2, W3, U2, U3, kW, kU);
    xw_mfma<<<dim3(kN * kL), dim3(kTh), 0, stream>>>(x, W1, kW, xww);
    scan_mfma<<<dim3(kN), dim3(kTh), 0, stream>>>(xww, U1, kU, outs, hlast);
  } else {
    fused_kernel<<<dim3(kN), dim3(kTh), 0, stream>>>(x, W1, W2, W3, U1, U2, U3,
                                                     outs, hlast);
  }
}

// Round 4
// 702.299 us; speedup vs baseline: 1.0970x; 1.0970x over previous
//
#include <hip/hip_runtime.h>
#include <stdint.h>

// GruTl: tensor-factorized GRU, N=64, L=128, modes (32,16,8) -> (32,16,8).
// R5 (resubmit; previous round was an infra failure, kernel never ran):
// per-kernel GEMM2 assignment.
//  - scan_mfma keeps R4's LDS-traffic cut: wave owns (d-tile = w&1, ef-tiles
//    {w>>1, w>>1+4}); 12 ds_read_b128/wave/step, bK doubled (VGPR 128 is free:
//    scan is grid-limited to 1 block/CU).
//  - xw_mfma reverts to R2's register-light assignment (wave owns ef-tile = w,
//    both d-tiles; single bK[3][4]) to restore 3 blocks/CU occupancy (VGPR
//    128 -> ~72 cost us ~77us in R4). Its stores are remapped into the layout
//    scan consumes:
//      value (g,mt,i) on thread (w,q,r) is (d=mt*16+q*4+i, ef=w*16+r);
//      pos = ((((w&3)<<1)|mt)*64 + q*16 + r)*8 + (w>>2)*4 + i
//    (bijective inverse of scan's reader; verified algebraically).

constexpr int kN = 64;
constexpr int kL = 128;
constexpr int kA = 32, kB = 16, kC = 8;
constexpr int kBC = kB * kC;       // 128
constexpr int kTot = kA * kBC;     // 4096 elements per (n,l) tile
constexpr int kTS = kBC + 4;       // fused-fallback LDS stride
constexpr int kTh = 512;

constexpr int kHTS = 40;           // hT/xT row stride in bf16 (32 + 8 pad, 16B-aligned rows)
constexpr int kT1S = 136;          // t1L row stride in bf16 (128 + 8 pad)

typedef __attribute__((ext_vector_type(8))) short bf16x8;
typedef __attribute__((ext_vector_type(4))) float f32x4;

namespace {

__device__ __forceinline__ float bf2f(unsigned int u) { return __uint_as_float(u << 16); }
__device__ __forceinline__ unsigned int f2bf(float v) {
  unsigned int u = __float_as_uint(v);
  return (u + 0x7fffu + ((u >> 16) & 1u)) >> 16;   // round-to-nearest-even
}
__device__ __forceinline__ float sigmoid_f(float x) {
  return __fdividef(1.f, 1.f + __expf(-x));
}
__device__ __forceinline__ float tanh_f(float x) {
  return 1.f - __fdividef(2.f, 1.f + __expf(2.f * x));
}

__device__ __forceinline__ bf16x8 frag_from_lds(const unsigned short* p) {
  uint4 u = *(const uint4*)p;
  return __builtin_bit_cast(bf16x8, u);
}
// 8 consecutive f32 -> bf16 frag (element j = input j)
__device__ __forceinline__ bf16x8 frag_from_f32(const float* p) {
  float4 a = ((const float4*)p)[0];
  float4 b = ((const float4*)p)[1];
  uint4 u;
  u.x = f2bf(a.x) | (f2bf(a.y) << 16);
  u.y = f2bf(a.z) | (f2bf(a.w) << 16);
  u.z = f2bf(b.x) | (f2bf(b.y) << 16);
  u.w = f2bf(b.z) | (f2bf(b.w) << 16);
  return __builtin_bit_cast(bf16x8, u);
}
__device__ __forceinline__ uint2 pack4(const f32x4& a) {
  uint2 p;
  p.x = f2bf(a[0]) | (f2bf(a[1]) << 16);
  p.y = f2bf(a[2]) | (f2bf(a[3]) << 16);
  return p;
}

// ---------------- kron precompute: kW/kU[g][ef][bc] = M2[g][e][b]*M3[g][f][c]
__global__ void kron_kernel(const float* __restrict__ W2, const float* __restrict__ W3,
                            const float* __restrict__ U2, const float* __restrict__ U3,
                            unsigned short* __restrict__ kW, unsigned short* __restrict__ kU) {
  int i = blockIdx.x * 256 + threadIdx.x;           // 0 .. 98303
  const float* M2 = W2; const float* M3 = W3; unsigned short* dst = kW;
  int j = i;
  if (i >= 3 * 128 * 128) { M2 = U2; M3 = U3; dst = kU; j = i - 3 * 128 * 128; }
  int g = j >> 14, ef = (j >> 7) & 127, bc = j & 127;
  int e = ef >> 3, f = ef & 7, b = bc >> 3, c = bc & 7;
  float v = M2[(g * 16 + e) * 16 + b] * M3[(g * 8 + f) * 8 + c];
  dst[j] = (unsigned short)f2bf(v);
}

// Shared GEMM1: out1T[bc][d] = sum_a srcT[bc][a] * M1T[a][d], written as t1L[d][bc].
// Wave w owns bc-tile w. a-frag = srcT row (w*16+r), cols q*8..+8, reused for 3 gates.
__device__ __forceinline__ void gemm1(const unsigned short* __restrict__ srcT,
                                      const bf16x8 bW[3][2],
                                      unsigned short (*__restrict__ t1L)[kA * kT1S],
                                      int w, int q, int r) {
  bf16x8 ah = frag_from_lds(srcT + (w * 16 + r) * kHTS + q * 8);
#pragma unroll
  for (int g = 0; g < 3; ++g) {
#pragma unroll
    for (int nt = 0; nt < 2; ++nt) {
      f32x4 acc = {0.f, 0.f, 0.f, 0.f};
      acc = __builtin_amdgcn_mfma_f32_16x16x32_bf16(ah, bW[g][nt], acc, 0, 0, 0);
      // D[bc = w*16+q*4+i][d = nt*16+r] -> t1L[g][d][bc], 4 consecutive bc
      *(uint2*)&t1L[g][(nt * 16 + r) * kT1S + w * 16 + q * 4] = pack4(acc);
    }
  }
}

// scan GEMM2 (R4 assignment): wave owns d-tile mtw = w&1 and ef-tiles
// {efb, efb+4} (efb = w>>1). A-frags depend only on (mtw,kc) -> 12 ds_read_b128
// per wave per step, reused across the 2 ef-tiles.
// out2[g][eft]: D[d = mtw*16+q*4+i][ef = (efb+4*eft)*16+r]
__device__ __forceinline__ void gemm2_scan(const unsigned short (*__restrict__ t1L)[kA * kT1S],
                                           const bf16x8 bK[3][2][4],
                                           f32x4 out2[3][2],
                                           int mtw, int q, int r) {
  const int abase = (mtw * 16 + r) * kT1S + q * 8;
#pragma unroll
  for (int g = 0; g < 3; ++g) {
    bf16x8 af[4];
#pragma unroll
    for (int kc = 0; kc < 4; ++kc)
      af[kc] = frag_from_lds(&t1L[g][abase + kc * 32]);
#pragma unroll
    for (int eft = 0; eft < 2; ++eft) {
      f32x4 acc = {0.f, 0.f, 0.f, 0.f};
#pragma unroll
      for (int kc = 0; kc < 4; ++kc)
        acc = __builtin_amdgcn_mfma_f32_16x16x32_bf16(af[kc], bK[g][eft][kc], acc, 0, 0, 0);
      out2[g][eft] = acc;
    }
  }
}

// scan B-frags: bK[g][eft][kc] (kron rows ef = (efb+4*eft)*16+r), bW[g][nt] from M1 (f32)
__device__ __forceinline__ void load_bfrags_scan(const unsigned short* __restrict__ kron,
                                                 const float* __restrict__ M1,
                                                 bf16x8 bK[3][2][4], bf16x8 bW[3][2],
                                                 int efb, int q, int r) {
#pragma unroll
  for (int g = 0; g < 3; ++g) {
#pragma unroll
    for (int eft = 0; eft < 2; ++eft)
#pragma unroll
      for (int kc = 0; kc < 4; ++kc)
        bK[g][eft][kc] = frag_from_lds(
            kron + ((g * 128 + (efb + 4 * eft) * 16 + r) * 128 + kc * 32 + q * 8));
#pragma unroll
    for (int nt = 0; nt < 2; ++nt)
      bW[g][nt] = frag_from_f32(M1 + (g * 32 + nt * 16 + r) * 32 + q * 8);
  }
}

// ---------------- kernel A: XW precompute via MFMA, one block per (n,l) --------
// R2 register-light assignment (wave owns ef-tile w, both d-tiles), stores
// remapped into scan's R4 fragment layout.
__global__ __launch_bounds__(kTh) void xw_mfma(
    const float* __restrict__ x, const float* __restrict__ W1,
    const unsigned short* __restrict__ kW, unsigned short* __restrict__ xw) {
  __shared__ __align__(16) unsigned short xT[kBC * kHTS];
  __shared__ __align__(16) unsigned short t1L[3][kA * kT1S];
  const int tid = threadIdx.x;
  const int blk = blockIdx.x;                       // n*L + t
  const int w = tid >> 6, l = tid & 63, q = l >> 4, r = l & 15;

  bf16x8 bK[3][4], bW[3][2];
#pragma unroll
  for (int g = 0; g < 3; ++g) {
#pragma unroll
    for (int kc = 0; kc < 4; ++kc)
      bK[g][kc] = frag_from_lds(kW + ((g * 128 + w * 16 + r) * 128 + kc * 32 + q * 8));
#pragma unroll
    for (int nt = 0; nt < 2; ++nt)
      bW[g][nt] = frag_from_f32(W1 + (g * 32 + nt * 16 + r) * 32 + q * 8);
  }

  // stage x tile -> xT[bc][a] (bf16). thread: fixed bc, 8 consecutive a.
  {
    const int bc = tid & 127, a0 = (tid >> 7) * 8;
    const float* xg = x + (size_t)blk * kTot + bc;
    uint4 u;
    u.x = f2bf(xg[(a0 + 0) * kBC]) | (f2bf(xg[(a0 + 1) * kBC]) << 16);
    u.y = f2bf(xg[(a0 + 2) * kBC]) | (f2bf(xg[(a0 + 3) * kBC]) << 16);
    u.z = f2bf(xg[(a0 + 4) * kBC]) | (f2bf(xg[(a0 + 5) * kBC]) << 16);
    u.w = f2bf(xg[(a0 + 6) * kBC]) | (f2bf(xg[(a0 + 7) * kBC]) << 16);
    *(uint4*)&xT[bc * kHTS + a0] = u;
  }
  __syncthreads();
  gemm1(xT, bW, t1L, w, q, r);
  __syncthreads();
  // R2 GEMM2: out2[g][mt]: D[d = mt*16+q*4+i][ef = w*16+r]
  f32x4 out2[3][2];
#pragma unroll
  for (int g = 0; g < 3; ++g) {
#pragma unroll
    for (int mt = 0; mt < 2; ++mt) {
      f32x4 acc = {0.f, 0.f, 0.f, 0.f};
#pragma unroll
      for (int kc = 0; kc < 4; ++kc) {
        bf16x8 af = frag_from_lds(&t1L[g][(mt * 16 + r) * kT1S + kc * 32 + q * 8]);
        acc = __builtin_amdgcn_mfma_f32_16x16x32_bf16(af, bK[g][kc], acc, 0, 0, 0);
      }
      out2[g][mt] = acc;
    }
  }
  // Remapped store into scan's layout:
  //   consumer thread w' = ((w&3)<<1)|mt, q'=q, r'=r, eft = w>>2, elements i.
  //   pos = (w'*64 + q*16 + r)*8 + eft*4 + i
  const int eftOfs = (w >> 2) * 4;
#pragma unroll
  for (int g = 0; g < 3; ++g) {
    unsigned short* xo = xw + ((size_t)blk * 3 + g) * kTot;
#pragma unroll
    for (int mt = 0; mt < 2; ++mt) {
      const int wp = ((w & 3) << 1) | mt;
      uint2 p = pack4(out2[g][mt]);
      *(uint2*)(xo + (wp * 64 + q * 16 + r) * 8 + eftOfs) = p;
    }
  }
}

// ---------------- kernel B: MFMA scan, one block per n ----------------
__global__ __launch_bounds__(kTh) void scan_mfma(
    const unsigned short* __restrict__ xw, const float* __restrict__ U1,
    const unsigned short* __restrict__ kU,
    float* __restrict__ outs, float* __restrict__ hlast) {
  __shared__ __align__(16) unsigned short hT[kBC * kHTS];
  __shared__ __align__(16) unsigned short t1L[3][kA * kT1S];
  const int tid = threadIdx.x;
  const int n = blockIdx.x;
  const int w = tid >> 6, l = tid & 63, q = l >> 4, r = l & 15;
  const int mtw = w & 1, efb = w >> 1;
  const int dbase = mtw * 16 + q * 4;

  bf16x8 bK[3][2][4], bW[3][2];
  load_bfrags_scan(kU, U1, bK, bW, efb, q, r);

  // zero hT
  for (int i = tid; i < kBC * kHTS / 2; i += kTh) ((unsigned int*)hT)[i] = 0u;
  float hreg[2][4] = {{0.f, 0.f, 0.f, 0.f}, {0.f, 0.f, 0.f, 0.f}};

  const unsigned short* xp = xw + (size_t)n * kL * 3 * kTot + tid * 8;
  unsigned int xc[3][4];
#pragma unroll
  for (int g = 0; g < 3; ++g) {
    uint4 u = *(const uint4*)(xp + g * kTot);
    xc[g][0] = u.x; xc[g][1] = u.y; xc[g][2] = u.z; xc[g][3] = u.w;
  }
  __syncthreads();

  for (int t = 0; t < kL; ++t) {
    // prefetch next step's xw
    unsigned int xn[3][4];
    {
      const unsigned short* xq = xp + (size_t)((t + 1 < kL) ? t + 1 : t) * 3 * kTot;
#pragma unroll
      for (int g = 0; g < 3; ++g) {
        uint4 u = *(const uint4*)(xq + g * kTot);
        xn[g][0] = u.x; xn[g][1] = u.y; xn[g][2] = u.z; xn[g][3] = u.w;
      }
    }
    gemm1(hT, bW, t1L, w, q, r);
    __syncthreads();
    f32x4 hu[3][2];
    gemm2_scan(t1L, bK, hu, mtw, q, r);

    // elementwise GRU on owned elements (d = dbase+i, ef = (efb+4*eft)*16+r)
    const size_t obase = ((size_t)n * kL + t) * kTot;
#pragma unroll
    for (int eft = 0; eft < 2; ++eft) {
      const int ef = (efb + 4 * eft) * 16 + r;
#pragma unroll
      for (int i = 0; i < 4; ++i) {
        const int e2 = eft * 4 + i;
        float x0 = bf2f((e2 & 1) ? (xc[0][e2 >> 1] >> 16) : (xc[0][e2 >> 1] & 0xffffu));
        float x1 = bf2f((e2 & 1) ? (xc[1][e2 >> 1] >> 16) : (xc[1][e2 >> 1] & 0xffffu));
        float x2 = bf2f((e2 & 1) ? (xc[2][e2 >> 1] >> 16) : (xc[2][e2 >> 1] & 0xffffu));
        float z  = sigmoid_f(x0 + hu[0][eft][i]);
        float rr = sigmoid_f(x1 + hu[1][eft][i]);
        float hc = tanh_f(x2 + rr * hu[2][eft][i]);
        float hn = z * hreg[eft][i] + (1.f - z) * hc;
        hreg[eft][i] = hn;
        outs[obase + (size_t)(dbase + i) * kBC + ef] = hn;
      }
      // write updated h (bf16) for next step's GEMM1: hT[ef][d], 4 consecutive d
      uint2 p;
      p.x = f2bf(hreg[eft][0]) | (f2bf(hreg[eft][1]) << 16);
      p.y = f2bf(hreg[eft][2]) | (f2bf(hreg[eft][3]) << 16);
      *(uint2*)&hT[ef * kHTS + dbase] = p;
    }
#pragma unroll
    for (int g = 0; g < 3; ++g)
#pragma unroll
      for (int u = 0; u < 4; ++u) xc[g][u] = xn[g][u];
    __syncthreads();
  }
#pragma unroll
  for (int eft = 0; eft < 2; ++eft) {
    const int ef = (efb + 4 * eft) * 16 + r;
#pragma unroll
    for (int i = 0; i < 4; ++i)
      hlast[(size_t)n * kTot + (size_t)(dbase + i) * kBC + ef] = hreg[eft][i];
  }
}

// ---------------- fallback: fully fused fp32 (validated structure, slow) -------
__device__ __forceinline__ int rfl(int v) { return __builtin_amdgcn_readfirstlane(v); }

__device__ __forceinline__ void load8f(const float* p, float* v) {
  float4 a = ((const float4*)p)[0];
  float4 b = ((const float4*)p)[1];
  v[0]=a.x; v[1]=a.y; v[2]=a.z; v[3]=a.w;
  v[4]=b.x; v[5]=b.y; v[6]=b.z; v[7]=b.w;
}
__device__ __forceinline__ void store8f(float* p, const float* v) {
  ((float4*)p)[0] = make_float4(v[0],v[1],v[2],v[3]);
  ((float4*)p)[1] = make_float4(v[4],v[5],v[6],v[7]);
}

__device__ __forceinline__ void mode1(const float* __restrict__ src,
                                      const float* __restrict__ Wg,
                                      float* __restrict__ t1, int tid) {
  const int w = rfl(tid >> 6);
  const int lane = tid & 63;
  const int bc = ((w & 1) << 6) | lane;
  const int dq = (w >> 1) << 3;
  float xr[kA];
#pragma unroll
  for (int a = 0; a < kA; ++a) xr[a] = src[a * kBC + bc];
  const float* wp = Wg + dq * kA;
#pragma unroll
  for (int dd = 0; dd < 8; ++dd) {
    float s = 0.f;
#pragma unroll
    for (int a = 0; a < kA; ++a) s += wp[dd * kA + a] * xr[a];
    t1[(dq + dd) * kTS + bc] = s;
  }
}
__device__ __forceinline__ void mode2(const float* __restrict__ t1,
                                      const float* __restrict__ Wg,
                                      float* __restrict__ t2, int tid) {
  const int w = rfl(tid >> 6);
  const int lane = tid & 63;
  const int d = ((w >> 1) << 3) | (lane >> 3);
  const int c = lane & 7;
  const int eh = (w & 1) << 3;
  float tr[kB];
#pragma unroll
  for (int b = 0; b < kB; ++b) tr[b] = t1[d * kTS + b * kC + c];
#pragma unroll
  for (int ee = 0; ee < 8; ++ee) {
    const int e = eh + ee;
    float s = 0.f;
#pragma unroll
    for (int b = 0; b < kB; ++b) s += Wg[e * kB + b] * tr[b];
    t2[d * kTS + e * kC + c] = s;
  }
}
__device__ __forceinline__ void mode3(const float* __restrict__ t2,
                                      const float* __restrict__ Wg,
                                      float* __restrict__ out8, int tid) {
  const int e = tid & 15;
  const int d = tid >> 4;
  float tr[kC];
  load8f(t2 + d * kTS + e * kC, tr);
#pragma unroll
  for (int f = 0; f < kC; ++f) {
    float s = 0.f;
#pragma unroll
    for (int c = 0; c < kC; ++c) s += Wg[f * kC + c] * tr[c];
    out8[f] = s;
  }
}

__global__ __launch_bounds__(kTh) void fused_kernel(
    const float* __restrict__ x,
    const float* __restrict__ W1, const float* __restrict__ W2,
    const float* __restrict__ W3, const float* __restrict__ U1,
    const float* __restrict__ U2, const float* __restrict__ U3,
    float* __restrict__ outs, float* __restrict__ hlast) {
  __shared__ float h[kTot];
  __shared__ float xs[kTot];
  __shared__ float t1[kA * kTS];
  __shared__ float t2[kA * kTS];
  const int tid = threadIdx.x;
  const int n = blockIdx.x;
  for (int i = tid; i < kTot; i += kTh) h[i] = 0.f;
  const int off = tid * kC;
  float* hp = h + off;
  float hn[kC];
  for (int l = 0; l < kL; ++l) {
    const float4* xg = (const float4*)(x + ((size_t)n * kL + l) * kTot);
    float4 xa = xg[tid], xb = xg[tid + kTh];
    __syncthreads();
    float4* xs4 = (float4*)xs;
    xs4[tid] = xa;
    xs4[tid + kTh] = xb;
    __syncthreads();
    float xwv[3][kC], hu[3][kC];
#pragma unroll
    for (int g = 0; g < 3; ++g) {
      mode1(xs, W1 + g * kA * kA, t1, tid);
      __syncthreads();
      mode2(t1, W2 + g * kB * kB, t2, tid);
      __syncthreads();
      mode3(t2, W3 + g * kC * kC, xwv[g], tid);
    }
#pragma unroll
    for (int g = 0; g < 3; ++g) {
      mode1(h, U1 + g * kA * kA, t1, tid);
      __syncthreads();
      mode2(t1, U2 + g * kB * kB, t2, tid);
      __syncthreads();
      mode3(t2, U3 + g * kC * kC, hu[g], tid);
    }
    float ho[kC];
    load8f(hp, ho);
#pragma unroll
    for (int f = 0; f < kC; ++f) {
      float z  = sigmoid_f(xwv[0][f] + hu[0][f]);
      float rr = sigmoid_f(xwv[1][f] + hu[1][f]);
      float hh = tanh_f(xwv[2][f] + rr * hu[2][f]);
      hn[f] = z * ho[f] + (1.f - z) * hh;
    }
    store8f(hp, hn);
    store8f(outs + ((size_t)n * kL + l) * kTot + off, hn);
  }
  store8f(hlast + (size_t)n * kTot + off, hn);
}

}  // namespace

extern "C" void kernel_launch(void* const* d_in, const int* in_sizes, int n_in,
                              void* d_out, int out_size, void* d_ws, size_t ws_size,
                              hipStream_t stream) {
  const float* x  = (const float*)d_in[0];
  const float* W1 = (const float*)d_in[1];
  const float* W2 = (const float*)d_in[2];
  const float* W3 = (const float*)d_in[3];
  const float* U1 = (const float*)d_in[4];
  const float* U2 = (const float*)d_in[5];
  const float* U3 = (const float*)d_in[6];
  float* outs  = (float*)d_out;
  float* hlast = outs + (size_t)kN * kL * kTot;

  const size_t kron_elems = 3 * 128 * 128;                    // per kron matrix
  const size_t kron_bytes = 2 * kron_elems * sizeof(unsigned short);   // 96 KB
  const size_t xw_bytes   = (size_t)kN * kL * 3 * kTot * 2;   // ~201 MB bf16

  if (ws_size >= kron_bytes + xw_bytes) {
    unsigned short* kW  = (unsigned short*)d_ws;
    unsigned short* kU  = kW + kron_elems;
    unsigned short* xww = kU + kron_elems;
    kron_kernel<<<dim3(384), dim3(256), 0, stream>>>(W2, W3, U2, U3, kW, kU);
    xw_mfma<<<dim3(kN * kL), dim3(kTh), 0, stream>>>(x, W1, kW, xww);
    scan_mfma<<<dim3(kN), dim3(kTh), 0, stream>>>(xww, U1, kU, outs, hlast);
  } else {
    fused_kernel<<<dim3(kN), dim3(kTh), 0, stream>>>(x, W1, W2, W3, U1, U2, U3,
                                                     outs, hlast);
  }
}

// Round 5
// 600.202 us; speedup vs baseline: 1.2836x; 1.1701x over previous
//
#include <hip/hip_runtime.h>
#include <stdint.h>

// GruTl: tensor-factorized GRU, N=64, L=128, modes (32,16,8) -> (32,16,8).
// R6: batched xw_mfma. Evidence: total-scan ~350us but xw's HBM floor is ~55us;
// per-block weight-fragment gathers (bK: 256B-strided 16B/lane -> 64 distinct
// 64B lines per instr; bW duplicated across all 8 waves) generate ~5GB of
// L2-sector traffic across 8192 blocks. Fix: 8 (n,l) tiles per block (grid
// 1024), weights loaded once per block -> gather traffic /8.
// scan_mfma unchanged from R5 (347us, verified): wave owns (d-tile = w&1,
// ef-tiles {w>>1, w>>1+4}); xw stores remain remapped into scan's fragment
// layout: pos = ((((w&3)<<1)|mt)*64 + q*16 + r)*8 + (w>>2)*4 + i.

constexpr int kN = 64;
constexpr int kL = 128;
constexpr int kA = 32, kB = 16, kC = 8;
constexpr int kBC = kB * kC;       // 128
constexpr int kTot = kA * kBC;     // 4096 elements per (n,l) tile
constexpr int kTS = kBC + 4;       // fused-fallback LDS stride
constexpr int kTh = 512;
constexpr int kXwTiles = 8;        // (n,l) tiles per xw block

constexpr int kHTS = 40;           // hT/xT row stride in bf16 (32 + 8 pad, 16B-aligned rows)
constexpr int kT1S = 136;          // t1L row stride in bf16 (128 + 8 pad)

typedef __attribute__((ext_vector_type(8))) short bf16x8;
typedef __attribute__((ext_vector_type(4))) float f32x4;

namespace {

__device__ __forceinline__ float bf2f(unsigned int u) { return __uint_as_float(u << 16); }
__device__ __forceinline__ unsigned int f2bf(float v) {
  unsigned int u = __float_as_uint(v);
  return (u + 0x7fffu + ((u >> 16) & 1u)) >> 16;   // round-to-nearest-even
}
__device__ __forceinline__ float sigmoid_f(float x) {
  return __fdividef(1.f, 1.f + __expf(-x));
}
__device__ __forceinline__ float tanh_f(float x) {
  return 1.f - __fdividef(2.f, 1.f + __expf(2.f * x));
}

__device__ __forceinline__ bf16x8 frag_from_lds(const unsigned short* p) {
  uint4 u = *(const uint4*)p;
  return __builtin_bit_cast(bf16x8, u);
}
// 8 consecutive f32 -> bf16 frag (element j = input j)
__device__ __forceinline__ bf16x8 frag_from_f32(const float* p) {
  float4 a = ((const float4*)p)[0];
  float4 b = ((const float4*)p)[1];
  uint4 u;
  u.x = f2bf(a.x) | (f2bf(a.y) << 16);
  u.y = f2bf(a.z) | (f2bf(a.w) << 16);
  u.z = f2bf(b.x) | (f2bf(b.y) << 16);
  u.w = f2bf(b.z) | (f2bf(b.w) << 16);
  return __builtin_bit_cast(bf16x8, u);
}
__device__ __forceinline__ uint2 pack4(const f32x4& a) {
  uint2 p;
  p.x = f2bf(a[0]) | (f2bf(a[1]) << 16);
  p.y = f2bf(a[2]) | (f2bf(a[3]) << 16);
  return p;
}

// ---------------- kron precompute: kW/kU[g][ef][bc] = M2[g][e][b]*M3[g][f][c]
__global__ void kron_kernel(const float* __restrict__ W2, const float* __restrict__ W3,
                            const float* __restrict__ U2, const float* __restrict__ U3,
                            unsigned short* __restrict__ kW, unsigned short* __restrict__ kU) {
  int i = blockIdx.x * 256 + threadIdx.x;           // 0 .. 98303
  const float* M2 = W2; const float* M3 = W3; unsigned short* dst = kW;
  int j = i;
  if (i >= 3 * 128 * 128) { M2 = U2; M3 = U3; dst = kU; j = i - 3 * 128 * 128; }
  int g = j >> 14, ef = (j >> 7) & 127, bc = j & 127;
  int e = ef >> 3, f = ef & 7, b = bc >> 3, c = bc & 7;
  float v = M2[(g * 16 + e) * 16 + b] * M3[(g * 8 + f) * 8 + c];
  dst[j] = (unsigned short)f2bf(v);
}

// Shared GEMM1: out1T[bc][d] = sum_a srcT[bc][a] * M1T[a][d], written as t1L[d][bc].
// Wave w owns bc-tile w. a-frag = srcT row (w*16+r), cols q*8..+8, reused for 3 gates.
__device__ __forceinline__ void gemm1(const unsigned short* __restrict__ srcT,
                                      const bf16x8 bW[3][2],
                                      unsigned short (*__restrict__ t1L)[kA * kT1S],
                                      int w, int q, int r) {
  bf16x8 ah = frag_from_lds(srcT + (w * 16 + r) * kHTS + q * 8);
#pragma unroll
  for (int g = 0; g < 3; ++g) {
#pragma unroll
    for (int nt = 0; nt < 2; ++nt) {
      f32x4 acc = {0.f, 0.f, 0.f, 0.f};
      acc = __builtin_amdgcn_mfma_f32_16x16x32_bf16(ah, bW[g][nt], acc, 0, 0, 0);
      // D[bc = w*16+q*4+i][d = nt*16+r] -> t1L[g][d][bc], 4 consecutive bc
      *(uint2*)&t1L[g][(nt * 16 + r) * kT1S + w * 16 + q * 4] = pack4(acc);
    }
  }
}

// scan GEMM2 (R4 assignment): wave owns d-tile mtw = w&1 and ef-tiles
// {efb, efb+4} (efb = w>>1). A-frags depend only on (mtw,kc) -> 12 ds_read_b128
// per wave per step, reused across the 2 ef-tiles.
// out2[g][eft]: D[d = mtw*16+q*4+i][ef = (efb+4*eft)*16+r]
__device__ __forceinline__ void gemm2_scan(const unsigned short (*__restrict__ t1L)[kA * kT1S],
                                           const bf16x8 bK[3][2][4],
                                           f32x4 out2[3][2],
                                           int mtw, int q, int r) {
  const int abase = (mtw * 16 + r) * kT1S + q * 8;
#pragma unroll
  for (int g = 0; g < 3; ++g) {
    bf16x8 af[4];
#pragma unroll
    for (int kc = 0; kc < 4; ++kc)
      af[kc] = frag_from_lds(&t1L[g][abase + kc * 32]);
#pragma unroll
    for (int eft = 0; eft < 2; ++eft) {
      f32x4 acc = {0.f, 0.f, 0.f, 0.f};
#pragma unroll
      for (int kc = 0; kc < 4; ++kc)
        acc = __builtin_amdgcn_mfma_f32_16x16x32_bf16(af[kc], bK[g][eft][kc], acc, 0, 0, 0);
      out2[g][eft] = acc;
    }
  }
}

// scan B-frags: bK[g][eft][kc] (kron rows ef = (efb+4*eft)*16+r), bW[g][nt] from M1 (f32)
__device__ __forceinline__ void load_bfrags_scan(const unsigned short* __restrict__ kron,
                                                 const float* __restrict__ M1,
                                                 bf16x8 bK[3][2][4], bf16x8 bW[3][2],
                                                 int efb, int q, int r) {
#pragma unroll
  for (int g = 0; g < 3; ++g) {
#pragma unroll
    for (int eft = 0; eft < 2; ++eft)
#pragma unroll
      for (int kc = 0; kc < 4; ++kc)
        bK[g][eft][kc] = frag_from_lds(
            kron + ((g * 128 + (efb + 4 * eft) * 16 + r) * 128 + kc * 32 + q * 8));
#pragma unroll
    for (int nt = 0; nt < 2; ++nt)
      bW[g][nt] = frag_from_f32(M1 + (g * 32 + nt * 16 + r) * 32 + q * 8);
  }
}

// ---------------- kernel A: XW precompute via MFMA, kXwTiles (n,l) per block --
// R2 register-light GEMM2 assignment (wave owns ef-tile w, both d-tiles),
// weights loaded ONCE per block, 8 consecutive tiles processed in a loop.
// Stores remapped into scan's R4 fragment layout.
__global__ __launch_bounds__(kTh) void xw_mfma(
    const float* __restrict__ x, const float* __restrict__ W1,
    const unsigned short* __restrict__ kW, unsigned short* __restrict__ xw) {
  __shared__ __align__(16) unsigned short xT[kBC * kHTS];
  __shared__ __align__(16) unsigned short t1L[3][kA * kT1S];
  const int tid = threadIdx.x;
  const int w = tid >> 6, l = tid & 63, q = l >> 4, r = l & 15;

  bf16x8 bK[3][4], bW[3][2];
#pragma unroll
  for (int g = 0; g < 3; ++g) {
#pragma unroll
    for (int kc = 0; kc < 4; ++kc)
      bK[g][kc] = frag_from_lds(kW + ((g * 128 + w * 16 + r) * 128 + kc * 32 + q * 8));
#pragma unroll
    for (int nt = 0; nt < 2; ++nt)
      bW[g][nt] = frag_from_f32(W1 + (g * 32 + nt * 16 + r) * 32 + q * 8);
  }

  // staging indices (loop-invariant)
  const int bc = tid & 127, a0 = (tid >> 7) * 8;
  const int eftOfs = (w >> 2) * 4;

  for (int tt = 0; tt < kXwTiles; ++tt) {
    const int blk = blockIdx.x * kXwTiles + tt;     // n*L + t

    // stage x tile -> xT[bc][a] (bf16). thread: fixed bc, 8 consecutive a.
    {
      const float* xg = x + (size_t)blk * kTot + bc;
      uint4 u;
      u.x = f2bf(xg[(a0 + 0) * kBC]) | (f2bf(xg[(a0 + 1) * kBC]) << 16);
      u.y = f2bf(xg[(a0 + 2) * kBC]) | (f2bf(xg[(a0 + 3) * kBC]) << 16);
      u.z = f2bf(xg[(a0 + 4) * kBC]) | (f2bf(xg[(a0 + 5) * kBC]) << 16);
      u.w = f2bf(xg[(a0 + 6) * kBC]) | (f2bf(xg[(a0 + 7) * kBC]) << 16);
      *(uint4*)&xT[bc * kHTS + a0] = u;
    }
    __syncthreads();
    gemm1(xT, bW, t1L, w, q, r);
    __syncthreads();
    // R2 GEMM2: out2[g][mt]: D[d = mt*16+q*4+i][ef = w*16+r]
    f32x4 out2[3][2];
#pragma unroll
    for (int g = 0; g < 3; ++g) {
#pragma unroll
      for (int mt = 0; mt < 2; ++mt) {
        f32x4 acc = {0.f, 0.f, 0.f, 0.f};
#pragma unroll
        for (int kc = 0; kc < 4; ++kc) {
          bf16x8 af = frag_from_lds(&t1L[g][(mt * 16 + r) * kT1S + kc * 32 + q * 8]);
          acc = __builtin_amdgcn_mfma_f32_16x16x32_bf16(af, bK[g][kc], acc, 0, 0, 0);
        }
        out2[g][mt] = acc;
      }
    }
    // Remapped store into scan's layout:
    //   consumer thread w' = ((w&3)<<1)|mt, q'=q, r'=r, eft = w>>2, elements i.
    //   pos = (w'*64 + q*16 + r)*8 + eft*4 + i
#pragma unroll
    for (int g = 0; g < 3; ++g) {
      unsigned short* xo = xw + ((size_t)blk * 3 + g) * kTot;
#pragma unroll
      for (int mt = 0; mt < 2; ++mt) {
        const int wp = ((w & 3) << 1) | mt;
        uint2 p = pack4(out2[g][mt]);
        *(uint2*)(xo + (wp * 64 + q * 16 + r) * 8 + eftOfs) = p;
      }
    }
    __syncthreads();   // protect xT (next stage) and t1L (next gemm1)
  }
}

// ---------------- kernel B: MFMA scan, one block per n ----------------
__global__ __launch_bounds__(kTh) void scan_mfma(
    const unsigned short* __restrict__ xw, const float* __restrict__ U1,
    const unsigned short* __restrict__ kU,
    float* __restrict__ outs, float* __restrict__ hlast) {
  __shared__ __align__(16) unsigned short hT[kBC * kHTS];
  __shared__ __align__(16) unsigned short t1L[3][kA * kT1S];
  const int tid = threadIdx.x;
  const int n = blockIdx.x;
  const int w = tid >> 6, l = tid & 63, q = l >> 4, r = l & 15;
  const int mtw = w & 1, efb = w >> 1;
  const int dbase = mtw * 16 + q * 4;

  bf16x8 bK[3][2][4], bW[3][2];
  load_bfrags_scan(kU, U1, bK, bW, efb, q, r);

  // zero hT
  for (int i = tid; i < kBC * kHTS / 2; i += kTh) ((unsigned int*)hT)[i] = 0u;
  float hreg[2][4] = {{0.f, 0.f, 0.f, 0.f}, {0.f, 0.f, 0.f, 0.f}};

  const unsigned short* xp = xw + (size_t)n * kL * 3 * kTot + tid * 8;
  unsigned int xc[3][4];
#pragma unroll
  for (int g = 0; g < 3; ++g) {
    uint4 u = *(const uint4*)(xp + g * kTot);
    xc[g][0] = u.x; xc[g][1] = u.y; xc[g][2] = u.z; xc[g][3] = u.w;
  }
  __syncthreads();

  for (int t = 0; t < kL; ++t) {
    // prefetch next step's xw
    unsigned int xn[3][4];
    {
      const unsigned short* xq = xp + (size_t)((t + 1 < kL) ? t + 1 : t) * 3 * kTot;
#pragma unroll
      for (int g = 0; g < 3; ++g) {
        uint4 u = *(const uint4*)(xq + g * kTot);
        xn[g][0] = u.x; xn[g][1] = u.y; xn[g][2] = u.z; xn[g][3] = u.w;
      }
    }
    gemm1(hT, bW, t1L, w, q, r);
    __syncthreads();
    f32x4 hu[3][2];
    gemm2_scan(t1L, bK, hu, mtw, q, r);

    // elementwise GRU on owned elements (d = dbase+i, ef = (efb+4*eft)*16+r)
    const size_t obase = ((size_t)n * kL + t) * kTot;
#pragma unroll
    for (int eft = 0; eft < 2; ++eft) {
      const int ef = (efb + 4 * eft) * 16 + r;
#pragma unroll
      for (int i = 0; i < 4; ++i) {
        const int e2 = eft * 4 + i;
        float x0 = bf2f((e2 & 1) ? (xc[0][e2 >> 1] >> 16) : (xc[0][e2 >> 1] & 0xffffu));
        float x1 = bf2f((e2 & 1) ? (xc[1][e2 >> 1] >> 16) : (xc[1][e2 >> 1] & 0xffffu));
        float x2 = bf2f((e2 & 1) ? (xc[2][e2 >> 1] >> 16) : (xc[2][e2 >> 1] & 0xffffu));
        float z  = sigmoid_f(x0 + hu[0][eft][i]);
        float rr = sigmoid_f(x1 + hu[1][eft][i]);
        float hc = tanh_f(x2 + rr * hu[2][eft][i]);
        float hn = z * hreg[eft][i] + (1.f - z) * hc;
        hreg[eft][i] = hn;
        outs[obase + (size_t)(dbase + i) * kBC + ef] = hn;
      }
      // write updated h (bf16) for next step's GEMM1: hT[ef][d], 4 consecutive d
      uint2 p;
      p.x = f2bf(hreg[eft][0]) | (f2bf(hreg[eft][1]) << 16);
      p.y = f2bf(hreg[eft][2]) | (f2bf(hreg[eft][3]) << 16);
      *(uint2*)&hT[ef * kHTS + dbase] = p;
    }
#pragma unroll
    for (int g = 0; g < 3; ++g)
#pragma unroll
      for (int u = 0; u < 4; ++u) xc[g][u] = xn[g][u];
    __syncthreads();
  }
#pragma unroll
  for (int eft = 0; eft < 2; ++eft) {
    const int ef = (efb + 4 * eft) * 16 + r;
#pragma unroll
    for (int i = 0; i < 4; ++i)
      hlast[(size_t)n * kTot + (size_t)(dbase + i) * kBC + ef] = hreg[eft][i];
  }
}

// ---------------- fallback: fully fused fp32 (validated structure, slow) -------
__device__ __forceinline__ int rfl(int v) { return __builtin_amdgcn_readfirstlane(v); }

__device__ __forceinline__ void load8f(const float* p, float* v) {
  float4 a = ((const float4*)p)[0];
  float4 b = ((const float4*)p)[1];
  v[0]=a.x; v[1]=a.y; v[2]=a.z; v[3]=a.w;
  v[4]=b.x; v[5]=b.y; v[6]=b.z; v[7]=b.w;
}
__device__ __forceinline__ void store8f(float* p, const float* v) {
  ((float4*)p)[0] = make_float4(v[0],v[1],v[2],v[3]);
  ((float4*)p)[1] = make_float4(v[4],v[5],v[6],v[7]);
}

__device__ __forceinline__ void mode1(const float* __restrict__ src,
                                      const float* __restrict__ Wg,
                                      float* __restrict__ t1, int tid) {
  const int w = rfl(tid >> 6);
  const int lane = tid & 63;
  const int bc = ((w & 1) << 6) | lane;
  const int dq = (w >> 1) << 3;
  float xr[kA];
#pragma unroll
  for (int a = 0; a < kA; ++a) xr[a] = src[a * kBC + bc];
  const float* wp = Wg + dq * kA;
#pragma unroll
  for (int dd = 0; dd < 8; ++dd) {
    float s = 0.f;
#pragma unroll
    for (int a = 0; a < kA; ++a) s += wp[dd * kA + a] * xr[a];
    t1[(dq + dd) * kTS + bc] = s;
  }
}
__device__ __forceinline__ void mode2(const float* __restrict__ t1,
                                      const float* __restrict__ Wg,
                                      float* __restrict__ t2, int tid) {
  const int w = rfl(tid >> 6);
  const int lane = tid & 63;
  const int d = ((w >> 1) << 3) | (lane >> 3);
  const int c = lane & 7;
  const int eh = (w & 1) << 3;
  float tr[kB];
#pragma unroll
  for (int b = 0; b < kB; ++b) tr[b] = t1[d * kTS + b * kC + c];
#pragma unroll
  for (int ee = 0; ee < 8; ++ee) {
    const int e = eh + ee;
    float s = 0.f;
#pragma unroll
    for (int b = 0; b < kB; ++b) s += Wg[e * kB + b] * tr[b];
    t2[d * kTS + e * kC + c] = s;
  }
}
__device__ __forceinline__ void mode3(const float* __restrict__ t2,
                                      const float* __restrict__ Wg,
                                      float* __restrict__ out8, int tid) {
  const int e = tid & 15;
  const int d = tid >> 4;
  float tr[kC];
  load8f(t2 + d * kTS + e * kC, tr);
#pragma unroll
  for (int f = 0; f < kC; ++f) {
    float s = 0.f;
#pragma unroll
    for (int c = 0; c < kC; ++c) s += Wg[f * kC + c] * tr[c];
    out8[f] = s;
  }
}

__global__ __launch_bounds__(kTh) void fused_kernel(
    const float* __restrict__ x,
    const float* __restrict__ W1, const float* __restrict__ W2,
    const float* __restrict__ W3, const float* __restrict__ U1,
    const float* __restrict__ U2, const float* __restrict__ U3,
    float* __restrict__ outs, float* __restrict__ hlast) {
  __shared__ float h[kTot];
  __shared__ float xs[kTot];
  __shared__ float t1[kA * kTS];
  __shared__ float t2[kA * kTS];
  const int tid = threadIdx.x;
  const int n = blockIdx.x;
  for (int i = tid; i < kTot; i += kTh) h[i] = 0.f;
  const int off = tid * kC;
  float* hp = h + off;
  float hn[kC];
  for (int l = 0; l < kL; ++l) {
    const float4* xg = (const float4*)(x + ((size_t)n * kL + l) * kTot);
    float4 xa = xg[tid], xb = xg[tid + kTh];
    __syncthreads();
    float4* xs4 = (float4*)xs;
    xs4[tid] = xa;
    xs4[tid + kTh] = xb;
    __syncthreads();
    float xwv[3][kC], hu[3][kC];
#pragma unroll
    for (int g = 0; g < 3; ++g) {
      mode1(xs, W1 + g * kA * kA, t1, tid);
      __syncthreads();
      mode2(t1, W2 + g * kB * kB, t2, tid);
      __syncthreads();
      mode3(t2, W3 + g * kC * kC, xwv[g], tid);
    }
#pragma unroll
    for (int g = 0; g < 3; ++g) {
      mode1(h, U1 + g * kA * kA, t1, tid);
      __syncthreads();
      mode2(t1, U2 + g * kB * kB, t2, tid);
      __syncthreads();
      mode3(t2, U3 + g * kC * kC, hu[g], tid);
    }
    float ho[kC];
    load8f(hp, ho);
#pragma unroll
    for (int f = 0; f < kC; ++f) {
      float z  = sigmoid_f(xwv[0][f] + hu[0][f]);
      float rr = sigmoid_f(xwv[1][f] + hu[1][f]);
      float hh = tanh_f(xwv[2][f] + rr * hu[2][f]);
      hn[f] = z * ho[f] + (1.f - z) * hh;
    }
    store8f(hp, hn);
    store8f(outs + ((size_t)n * kL + l) * kTot + off, hn);
  }
  store8f(hlast + (size_t)n * kTot + off, hn);
}

}  // namespace

extern "C" void kernel_launch(void* const* d_in, const int* in_sizes, int n_in,
                              void* d_out, int out_size, void* d_ws, size_t ws_size,
                              hipStream_t stream) {
  const float* x  = (const float*)d_in[0];
  const float* W1 = (const float*)d_in[1];
  const float* W2 = (const float*)d_in[2];
  const float* W3 = (const float*)d_in[3];
  const float* U1 = (const float*)d_in[4];
  const float* U2 = (const float*)d_in[5];
  const float* U3 = (const float*)d_in[6];
  float* outs  = (float*)d_out;
  float* hlast = outs + (size_t)kN * kL * kTot;

  const size_t kron_elems = 3 * 128 * 128;                    // per kron matrix
  const size_t kron_bytes = 2 * kron_elems * sizeof(unsigned short);   // 96 KB
  const size_t xw_bytes   = (size_t)kN * kL * 3 * kTot * 2;   // ~201 MB bf16

  if (ws_size >= kron_bytes + xw_bytes) {
    unsigned short* kW  = (unsigned short*)d_ws;
    unsigned short* kU  = kW + kron_elems;
    unsigned short* xww = kU + kron_elems;
    kron_kernel<<<dim3(384), dim3(256), 0, stream>>>(W2, W3, U2, U3, kW, kU);
    xw_mfma<<<dim3(kN * kL / kXwTiles), dim3(kTh), 0, stream>>>(x, W1, kW, xww);
    scan_mfma<<<dim3(kN), dim3(kTh), 0, stream>>>(xww, U1, kU, outs, hlast);
  } else {
    fused_kernel<<<dim3(kN), dim3(kTh), 0, stream>>>(x, W1, W2, W3, U1, U2, U3,
                                                     outs, hlast);
  }
}

// Round 6
// 588.025 us; speedup vs baseline: 1.3102x; 1.0207x over previous
//
#include <hip/hip_runtime.h>
#include <stdint.h>

// GruTl: tensor-factorized GRU, N=64, L=128, modes (32,16,8) -> (32,16,8).
// R7: pipelined xw_mfma. R6 left xw at ~230us vs a ~55us HBM + ~47us LDS floor;
// the residual is the serial 8-tile chain per block: each tile's 8 global x
// loads are issued after the previous tile's end barrier (exposed ~900cy HBM
// latency) + 3 barriers/tile. Fix: 16 tiles/block (grid 512 = 2 blocks/CU,
// single round), xT double-buffer, next-tile x loads issued during gemm1 and
// landed during gemm2 (latency hidden), 2 barriers/tile.
// xw keeps the register-light R2 gemm2 (VGPR ~80: R4 showed dedup's VGPR cost
// hurts xw). scan_mfma unchanged from R6 (346us, verified).

constexpr int kN = 64;
constexpr int kL = 128;
constexpr int kA = 32, kB = 16, kC = 8;
constexpr int kBC = kB * kC;       // 128
constexpr int kTot = kA * kBC;     // 4096 elements per (n,l) tile
constexpr int kTS = kBC + 4;       // fused-fallback LDS stride
constexpr int kTh = 512;
constexpr int kXwTiles = 16;       // (n,l) tiles per xw block

constexpr int kHTS = 40;           // hT/xT row stride in bf16 (32 + 8 pad, 16B-aligned rows)
constexpr int kT1S = 136;          // t1L row stride in bf16 (128 + 8 pad)

typedef __attribute__((ext_vector_type(8))) short bf16x8;
typedef __attribute__((ext_vector_type(4))) float f32x4;

namespace {

__device__ __forceinline__ float bf2f(unsigned int u) { return __uint_as_float(u << 16); }
__device__ __forceinline__ unsigned int f2bf(float v) {
  unsigned int u = __float_as_uint(v);
  return (u + 0x7fffu + ((u >> 16) & 1u)) >> 16;   // round-to-nearest-even
}
__device__ __forceinline__ float sigmoid_f(float x) {
  return __fdividef(1.f, 1.f + __expf(-x));
}
__device__ __forceinline__ float tanh_f(float x) {
  return 1.f - __fdividef(2.f, 1.f + __expf(2.f * x));
}

__device__ __forceinline__ bf16x8 frag_from_lds(const unsigned short* p) {
  uint4 u = *(const uint4*)p;
  return __builtin_bit_cast(bf16x8, u);
}
// 8 consecutive f32 -> bf16 frag (element j = input j)
__device__ __forceinline__ bf16x8 frag_from_f32(const float* p) {
  float4 a = ((const float4*)p)[0];
  float4 b = ((const float4*)p)[1];
  uint4 u;
  u.x = f2bf(a.x) | (f2bf(a.y) << 16);
  u.y = f2bf(a.z) | (f2bf(a.w) << 16);
  u.z = f2bf(b.x) | (f2bf(b.y) << 16);
  u.w = f2bf(b.z) | (f2bf(b.w) << 16);
  return __builtin_bit_cast(bf16x8, u);
}
__device__ __forceinline__ uint2 pack4(const f32x4& a) {
  uint2 p;
  p.x = f2bf(a[0]) | (f2bf(a[1]) << 16);
  p.y = f2bf(a[2]) | (f2bf(a[3]) << 16);
  return p;
}
__device__ __forceinline__ uint4 pack8(const float* v) {
  uint4 u;
  u.x = f2bf(v[0]) | (f2bf(v[1]) << 16);
  u.y = f2bf(v[2]) | (f2bf(v[3]) << 16);
  u.z = f2bf(v[4]) | (f2bf(v[5]) << 16);
  u.w = f2bf(v[6]) | (f2bf(v[7]) << 16);
  return u;
}

// ---------------- kron precompute: kW/kU[g][ef][bc] = M2[g][e][b]*M3[g][f][c]
__global__ void kron_kernel(const float* __restrict__ W2, const float* __restrict__ W3,
                            const float* __restrict__ U2, const float* __restrict__ U3,
                            unsigned short* __restrict__ kW, unsigned short* __restrict__ kU) {
  int i = blockIdx.x * 256 + threadIdx.x;           // 0 .. 98303
  const float* M2 = W2; const float* M3 = W3; unsigned short* dst = kW;
  int j = i;
  if (i >= 3 * 128 * 128) { M2 = U2; M3 = U3; dst = kU; j = i - 3 * 128 * 128; }
  int g = j >> 14, ef = (j >> 7) & 127, bc = j & 127;
  int e = ef >> 3, f = ef & 7, b = bc >> 3, c = bc & 7;
  float v = M2[(g * 16 + e) * 16 + b] * M3[(g * 8 + f) * 8 + c];
  dst[j] = (unsigned short)f2bf(v);
}

// Shared GEMM1: out1T[bc][d] = sum_a srcT[bc][a] * M1T[a][d], written as t1L[d][bc].
// Wave w owns bc-tile w. a-frag = srcT row (w*16+r), cols q*8..+8, reused for 3 gates.
__device__ __forceinline__ void gemm1(const unsigned short* __restrict__ srcT,
                                      const bf16x8 bW[3][2],
                                      unsigned short (*__restrict__ t1L)[kA * kT1S],
                                      int w, int q, int r) {
  bf16x8 ah = frag_from_lds(srcT + (w * 16 + r) * kHTS + q * 8);
#pragma unroll
  for (int g = 0; g < 3; ++g) {
#pragma unroll
    for (int nt = 0; nt < 2; ++nt) {
      f32x4 acc = {0.f, 0.f, 0.f, 0.f};
      acc = __builtin_amdgcn_mfma_f32_16x16x32_bf16(ah, bW[g][nt], acc, 0, 0, 0);
      // D[bc = w*16+q*4+i][d = nt*16+r] -> t1L[g][d][bc], 4 consecutive bc
      *(uint2*)&t1L[g][(nt * 16 + r) * kT1S + w * 16 + q * 4] = pack4(acc);
    }
  }
}

// scan GEMM2 (R4 assignment): wave owns d-tile mtw = w&1 and ef-tiles
// {efb, efb+4} (efb = w>>1). A-frags depend only on (mtw,kc) -> 12 ds_read_b128
// per wave per step, reused across the 2 ef-tiles.
// out2[g][eft]: D[d = mtw*16+q*4+i][ef = (efb+4*eft)*16+r]
__device__ __forceinline__ void gemm2_scan(const unsigned short (*__restrict__ t1L)[kA * kT1S],
                                           const bf16x8 bK[3][2][4],
                                           f32x4 out2[3][2],
                                           int mtw, int q, int r) {
  const int abase = (mtw * 16 + r) * kT1S + q * 8;
#pragma unroll
  for (int g = 0; g < 3; ++g) {
    bf16x8 af[4];
#pragma unroll
    for (int kc = 0; kc < 4; ++kc)
      af[kc] = frag_from_lds(&t1L[g][abase + kc * 32]);
#pragma unroll
    for (int eft = 0; eft < 2; ++eft) {
      f32x4 acc = {0.f, 0.f, 0.f, 0.f};
#pragma unroll
      for (int kc = 0; kc < 4; ++kc)
        acc = __builtin_amdgcn_mfma_f32_16x16x32_bf16(af[kc], bK[g][eft][kc], acc, 0, 0, 0);
      out2[g][eft] = acc;
    }
  }
}

// scan B-frags: bK[g][eft][kc] (kron rows ef = (efb+4*eft)*16+r), bW[g][nt] from M1 (f32)
__device__ __forceinline__ void load_bfrags_scan(const unsigned short* __restrict__ kron,
                                                 const float* __restrict__ M1,
                                                 bf16x8 bK[3][2][4], bf16x8 bW[3][2],
                                                 int efb, int q, int r) {
#pragma unroll
  for (int g = 0; g < 3; ++g) {
#pragma unroll
    for (int eft = 0; eft < 2; ++eft)
#pragma unroll
      for (int kc = 0; kc < 4; ++kc)
        bK[g][eft][kc] = frag_from_lds(
            kron + ((g * 128 + (efb + 4 * eft) * 16 + r) * 128 + kc * 32 + q * 8));
#pragma unroll
    for (int nt = 0; nt < 2; ++nt)
      bW[g][nt] = frag_from_f32(M1 + (g * 32 + nt * 16 + r) * 32 + q * 8);
  }
}

// ---------------- kernel A: XW precompute via MFMA, kXwTiles (n,l) per block --
// R2 register-light GEMM2 assignment (wave owns ef-tile w, both d-tiles),
// weights loaded ONCE per block. Software-pipelined: next tile's x loads issue
// during gemm1 and land during gemm2 (xT double-buffered); 2 barriers/tile.
// Stores remapped into scan's R4 fragment layout.
__global__ __launch_bounds__(kTh) void xw_mfma(
    const float* __restrict__ x, const float* __restrict__ W1,
    const unsigned short* __restrict__ kW, unsigned short* __restrict__ xw) {
  __shared__ __align__(16) unsigned short xT[2][kBC * kHTS];
  __shared__ __align__(16) unsigned short t1L[3][kA * kT1S];
  const int tid = threadIdx.x;
  const int w = tid >> 6, l = tid & 63, q = l >> 4, r = l & 15;

  bf16x8 bK[3][4], bW[3][2];
#pragma unroll
  for (int g = 0; g < 3; ++g) {
#pragma unroll
    for (int kc = 0; kc < 4; ++kc)
      bK[g][kc] = frag_from_lds(kW + ((g * 128 + w * 16 + r) * 128 + kc * 32 + q * 8));
#pragma unroll
    for (int nt = 0; nt < 2; ++nt)
      bW[g][nt] = frag_from_f32(W1 + (g * 32 + nt * 16 + r) * 32 + q * 8);
  }

  // staging indices (loop-invariant)
  const int bc = tid & 127, a0 = (tid >> 7) * 8;
  const int eftOfs = (w >> 2) * 4;
  const int blk0 = blockIdx.x * kXwTiles;

  // prologue: load + stage tile 0
  float xr[8];
  {
    const float* xg = x + (size_t)blk0 * kTot + bc;
#pragma unroll
    for (int j = 0; j < 8; ++j) xr[j] = xg[(a0 + j) * kBC];
    *(uint4*)&xT[0][bc * kHTS + a0] = pack8(xr);
  }
  __syncthreads();

  for (int tt = 0; tt < kXwTiles; ++tt) {
    const int blk = blk0 + tt;
    // issue next tile's x loads (land during gemm2; clamped dup on last iter)
    {
      const int nx = (tt + 1 < kXwTiles) ? tt + 1 : tt;
      const float* xg = x + (size_t)(blk0 + nx) * kTot + bc;
#pragma unroll
      for (int j = 0; j < 8; ++j) xr[j] = xg[(a0 + j) * kBC];
    }
    gemm1(xT[tt & 1], bW, t1L, w, q, r);
    __syncthreads();
    // R2 GEMM2: out2[g][mt]: D[d = mt*16+q*4+i][ef = w*16+r]
    f32x4 out2[3][2];
#pragma unroll
    for (int g = 0; g < 3; ++g) {
#pragma unroll
      for (int mt = 0; mt < 2; ++mt) {
        f32x4 acc = {0.f, 0.f, 0.f, 0.f};
#pragma unroll
        for (int kc = 0; kc < 4; ++kc) {
          bf16x8 af = frag_from_lds(&t1L[g][(mt * 16 + r) * kT1S + kc * 32 + q * 8]);
          acc = __builtin_amdgcn_mfma_f32_16x16x32_bf16(af, bK[g][kc], acc, 0, 0, 0);
        }
        out2[g][mt] = acc;
      }
    }
    // Remapped store into scan's layout:
    //   consumer thread w' = ((w&3)<<1)|mt, q'=q, r'=r, eft = w>>2, elements i.
    //   pos = (w'*64 + q*16 + r)*8 + eft*4 + i
#pragma unroll
    for (int g = 0; g < 3; ++g) {
      unsigned short* xo = xw + ((size_t)blk * 3 + g) * kTot;
#pragma unroll
      for (int mt = 0; mt < 2; ++mt) {
        const int wp = ((w & 3) << 1) | mt;
        uint2 p = pack4(out2[g][mt]);
        *(uint2*)(xo + (wp * 64 + q * 16 + r) * 8 + eftOfs) = p;
      }
    }
    // stage next tile into the other xT buffer (read next iter after barrier)
    *(uint4*)&xT[(tt + 1) & 1][bc * kHTS + a0] = pack8(xr);
    __syncthreads();
  }
}

// ---------------- kernel B: MFMA scan, one block per n ----------------
__global__ __launch_bounds__(kTh) void scan_mfma(
    const unsigned short* __restrict__ xw, const float* __restrict__ U1,
    const unsigned short* __restrict__ kU,
    float* __restrict__ outs, float* __restrict__ hlast) {
  __shared__ __align__(16) unsigned short hT[kBC * kHTS];
  __shared__ __align__(16) unsigned short t1L[3][kA * kT1S];
  const int tid = threadIdx.x;
  const int n = blockIdx.x;
  const int w = tid >> 6, l = tid & 63, q = l >> 4, r = l & 15;
  const int mtw = w & 1, efb = w >> 1;
  const int dbase = mtw * 16 + q * 4;

  bf16x8 bK[3][2][4], bW[3][2];
  load_bfrags_scan(kU, U1, bK, bW, efb, q, r);

  // zero hT
  for (int i = tid; i < kBC * kHTS / 2; i += kTh) ((unsigned int*)hT)[i] = 0u;
  float hreg[2][4] = {{0.f, 0.f, 0.f, 0.f}, {0.f, 0.f, 0.f, 0.f}};

  const unsigned short* xp = xw + (size_t)n * kL * 3 * kTot + tid * 8;
  unsigned int xc[3][4];
#pragma unroll
  for (int g = 0; g < 3; ++g) {
    uint4 u = *(const uint4*)(xp + g * kTot);
    xc[g][0] = u.x; xc[g][1] = u.y; xc[g][2] = u.z; xc[g][3] = u.w;
  }
  __syncthreads();

  for (int t = 0; t < kL; ++t) {
    // prefetch next step's xw
    unsigned int xn[3][4];
    {
      const unsigned short* xq = xp + (size_t)((t + 1 < kL) ? t + 1 : t) * 3 * kTot;
#pragma unroll
      for (int g = 0; g < 3; ++g) {
        uint4 u = *(const uint4*)(xq + g * kTot);
        xn[g][0] = u.x; xn[g][1] = u.y; xn[g][2] = u.z; xn[g][3] = u.w;
      }
    }
    gemm1(hT, bW, t1L, w, q, r);
    __syncthreads();
    f32x4 hu[3][2];
    gemm2_scan(t1L, bK, hu, mtw, q, r);

    // elementwise GRU on owned elements (d = dbase+i, ef = (efb+4*eft)*16+r)
    const size_t obase = ((size_t)n * kL + t) * kTot;
#pragma unroll
    for (int eft = 0; eft < 2; ++eft) {
      const int ef = (efb + 4 * eft) * 16 + r;
#pragma unroll
      for (int i = 0; i < 4; ++i) {
        const int e2 = eft * 4 + i;
        float x0 = bf2f((e2 & 1) ? (xc[0][e2 >> 1] >> 16) : (xc[0][e2 >> 1] & 0xffffu));
        float x1 = bf2f((e2 & 1) ? (xc[1][e2 >> 1] >> 16) : (xc[1][e2 >> 1] & 0xffffu));
        float x2 = bf2f((e2 & 1) ? (xc[2][e2 >> 1] >> 16) : (xc[2][e2 >> 1] & 0xffffu));
        float z  = sigmoid_f(x0 + hu[0][eft][i]);
        float rr = sigmoid_f(x1 + hu[1][eft][i]);
        float hc = tanh_f(x2 + rr * hu[2][eft][i]);
        float hn = z * hreg[eft][i] + (1.f - z) * hc;
        hreg[eft][i] = hn;
        outs[obase + (size_t)(dbase + i) * kBC + ef] = hn;
      }
      // write updated h (bf16) for next step's GEMM1: hT[ef][d], 4 consecutive d
      uint2 p;
      p.x = f2bf(hreg[eft][0]) | (f2bf(hreg[eft][1]) << 16);
      p.y = f2bf(hreg[eft][2]) | (f2bf(hreg[eft][3]) << 16);
      *(uint2*)&hT[ef * kHTS + dbase] = p;
    }
#pragma unroll
    for (int g = 0; g < 3; ++g)
#pragma unroll
      for (int u = 0; u < 4; ++u) xc[g][u] = xn[g][u];
    __syncthreads();
  }
#pragma unroll
  for (int eft = 0; eft < 2; ++eft) {
    const int ef = (efb + 4 * eft) * 16 + r;
#pragma unroll
    for (int i = 0; i < 4; ++i)
      hlast[(size_t)n * kTot + (size_t)(dbase + i) * kBC + ef] = hreg[eft][i];
  }
}

// ---------------- fallback: fully fused fp32 (validated structure, slow) -------
__device__ __forceinline__ int rfl(int v) { return __builtin_amdgcn_readfirstlane(v); }

__device__ __forceinline__ void load8f(const float* p, float* v) {
  float4 a = ((const float4*)p)[0];
  float4 b = ((const float4*)p)[1];
  v[0]=a.x; v[1]=a.y; v[2]=a.z; v[3]=a.w;
  v[4]=b.x; v[5]=b.y; v[6]=b.z; v[7]=b.w;
}
__device__ __forceinline__ void store8f(float* p, const float* v) {
  ((float4*)p)[0] = make_float4(v[0],v[1],v[2],v[3]);
  ((float4*)p)[1] = make_float4(v[4],v[5],v[6],v[7]);
}

__device__ __forceinline__ void mode1(const float* __restrict__ src,
                                      const float* __restrict__ Wg,
                                      float* __restrict__ t1, int tid) {
  const int w = rfl(tid >> 6);
  const int lane = tid & 63;
  const int bc = ((w & 1) << 6) | lane;
  const int dq = (w >> 1) << 3;
  float xr[kA];
#pragma unroll
  for (int a = 0; a < kA; ++a) xr[a] = src[a * kBC + bc];
  const float* wp = Wg + dq * kA;
#pragma unroll
  for (int dd = 0; dd < 8; ++dd) {
    float s = 0.f;
#pragma unroll
    for (int a = 0; a < kA; ++a) s += wp[dd * kA + a] * xr[a];
    t1[(dq + dd) * kTS + bc] = s;
  }
}
__device__ __forceinline__ void mode2(const float* __restrict__ t1,
                                      const float* __restrict__ Wg,
                                      float* __restrict__ t2, int tid) {
  const int w = rfl(tid >> 6);
  const int lane = tid & 63;
  const int d = ((w >> 1) << 3) | (lane >> 3);
  const int c = lane & 7;
  const int eh = (w & 1) << 3;
  float tr[kB];
#pragma unroll
  for (int b = 0; b < kB; ++b) tr[b] = t1[d * kTS + b * kC + c];
#pragma unroll
  for (int ee = 0; ee < 8; ++ee) {
    const int e = eh + ee;
    float s = 0.f;
#pragma unroll
    for (int b = 0; b < kB; ++b) s += Wg[e * kB + b] * tr[b];
    t2[d * kTS + e * kC + c] = s;
  }
}
__device__ __forceinline__ void mode3(const float* __restrict__ t2,
                                      const float* __restrict__ Wg,
                                      float* __restrict__ out8, int tid) {
  const int e = tid & 15;
  const int d = tid >> 4;
  float tr[kC];
  load8f(t2 + d * kTS + e * kC, tr);
#pragma unroll
  for (int f = 0; f < kC; ++f) {
    float s = 0.f;
#pragma unroll
    for (int c = 0; c < kC; ++c) s += Wg[f * kC + c] * tr[c];
    out8[f] = s;
  }
}

__global__ __launch_bounds__(kTh) void fused_kernel(
    const float* __restrict__ x,
    const float* __restrict__ W1, const float* __restrict__ W2,
    const float* __restrict__ W3, const float* __restrict__ U1,
    const float* __restrict__ U2, const float* __restrict__ U3,
    float* __restrict__ outs, float* __restrict__ hlast) {
  __shared__ float h[kTot];
  __shared__ float xs[kTot];
  __shared__ float t1[kA * kTS];
  __shared__ float t2[kA * kTS];
  const int tid = threadIdx.x;
  const int n = blockIdx.x;
  for (int i = tid; i < kTot; i += kTh) h[i] = 0.f;
  const int off = tid * kC;
  float* hp = h + off;
  float hn[kC];
  for (int l = 0; l < kL; ++l) {
    const float4* xg = (const float4*)(x + ((size_t)n * kL + l) * kTot);
    float4 xa = xg[tid], xb = xg[tid + kTh];
    __syncthreads();
    float4* xs4 = (float4*)xs;
    xs4[tid] = xa;
    xs4[tid + kTh] = xb;
    __syncthreads();
    float xwv[3][kC], hu[3][kC];
#pragma unroll
    for (int g = 0; g < 3; ++g) {
      mode1(xs, W1 + g * kA * kA, t1, tid);
      __syncthreads();
      mode2(t1, W2 + g * kB * kB, t2, tid);
      __syncthreads();
      mode3(t2, W3 + g * kC * kC, xwv[g], tid);
    }
#pragma unroll
    for (int g = 0; g < 3; ++g) {
      mode1(h, U1 + g * kA * kA, t1, tid);
      __syncthreads();
      mode2(t1, U2 + g * kB * kB, t2, tid);
      __syncthreads();
      mode3(t2, U3 + g * kC * kC, hu[g], tid);
    }
    float ho[kC];
    load8f(hp, ho);
#pragma unroll
    for (int f = 0; f < kC; ++f) {
      float z  = sigmoid_f(xwv[0][f] + hu[0][f]);
      float rr = sigmoid_f(xwv[1][f] + hu[1][f]);
      float hh = tanh_f(xwv[2][f] + rr * hu[2][f]);
      hn[f] = z * ho[f] + (1.f - z) * hh;
    }
    store8f(hp, hn);
    store8f(outs + ((size_t)n * kL + l) * kTot + off, hn);
  }
  store8f(hlast + (size_t)n * kTot + off, hn);
}

}  // namespace

extern "C" void kernel_launch(void* const* d_in, const int* in_sizes, int n_in,
                              void* d_out, int out_size, void* d_ws, size_t ws_size,
                              hipStream_t stream) {
  const float* x  = (const float*)d_in[0];
  const float* W1 = (const float*)d_in[1];
  const float* W2 = (const float*)d_in[2];
  const float* W3 = (const float*)d_in[3];
  const float* U1 = (const float*)d_in[4];
  const float* U2 = (const float*)d_in[5];
  const float* U3 = (const float*)d_in[6];
  float* outs  = (float*)d_out;
  float* hlast = outs + (size_t)kN * kL * kTot;

  const size_t kron_elems = 3 * 128 * 128;                    // per kron matrix
  const size_t kron_bytes = 2 * kron_elems * sizeof(unsigned short);   // 96 KB
  const size_t xw_bytes   = (size_t)kN * kL * 3 * kTot * 2;   // ~201 MB bf16

  if (ws_size >= kron_bytes + xw_bytes) {
    unsigned short* kW  = (unsigned short*)d_ws;
    unsigned short* kU  = kW + kron_elems;
    unsigned short* xww = kU + kron_elems;
    kron_kernel<<<dim3(384), dim3(256), 0, stream>>>(W2, W3, U2, U3, kW, kU);
    xw_mfma<<<dim3(kN * kL / kXwTiles), dim3(kTh), 0, stream>>>(x, W1, kW, xww);
    scan_mfma<<<dim3(kN), dim3(kTh), 0, stream>>>(xww, U1, kU, outs, hlast);
  } else {
    fused_kernel<<<dim3(kN), dim3(kTh), 0, stream>>>(x, W1, W2, W3, U1, U2, U3,
                                                     outs, hlast);
  }
}